// Round 14
// baseline (147.942 us; speedup 1.0000x reference)
//
#include <hip/hip_runtime.h>
#include <math.h>

// Problem constants
#define B_TOT 2048
#define S_LEN 256
#define DIN   3
#define H     128
#define DOUT  6
#define DT_C  0.1f

#define NROWS 8    // batch rows per block (valid cols of the n=16 MFMA face)
#define HPAD  136  // bf16 row stride in sh_h (128 + 8 pad), rows 16B-aligned
#define PPAD  132  // f32 row stride in sh_p (head staging only)

// scale folded into W_hh/W_xh/b_hh so epilogue uses exp2 directly:
// tanh(p) = 1 - 2/(exp2(p * 2*log2e)+1)
#define PRESCALE 2.8853900817779268f   // 2*log2(e)

typedef __attribute__((ext_vector_type(8))) short short8;
typedef __attribute__((ext_vector_type(4))) float f32x4;

__device__ __forceinline__ unsigned short f2bf(float f) {
  unsigned int u = __float_as_uint(f);
  u += 0x7FFFu + ((u >> 16) & 1u);          // round-to-nearest-even
  return (unsigned short)(u >> 16);
}
// pack two f32 -> two bf16 (RNE) in one dword
__device__ __forceinline__ unsigned int pack2_bf16(float a, float b) {
  unsigned int ua = __float_as_uint(a), ub = __float_as_uint(b);
  ua = ua + 0x7FFFu + ((ua >> 16) & 1u);
  ub = ub + 0x7FFFu + ((ub >> 16) & 1u);
  return (ua >> 16) | (ub & 0xFFFF0000u);
}
// lane-pair exchange lane <-> lane^8 within 16-lane DPP row (full-rate VALU, no LDS)
__device__ __forceinline__ float dpp_xor8(float v) {
  int i = __float_as_int(v);
  int r = __builtin_amdgcn_update_dpp(i, i, 0x128 /*row_ror:8*/, 0xF, 0xF, false);
  return __int_as_float(r);
}

// One block = 8 batch rows, 512 threads (8 waves, 2/SIMD). Wave w owns j-tile
// [w*16, w*16+16); A = W_hh rows (PRESCALEd, plain bf16 RNE, register-resident).
//   MFMA: D[m=j_loc][n=b] ; lane holds (b = lane&15, j_loc = quad*4 + r).
// DENSE epilogue via DPP: lane b keeps regs r=0,1; partner lane b+8 receives
// r=2,3 via row_ror:8. Every lane owns 2 elems
// (b = l16&7, j = w*16 + quad*4 + (l16>>3)*2 + {0,1}) for all 256 steps.
// B-frag LDS reads exec-masked to l16<8 (R13 showed 64-lane broadcast reads
// cost full LDS bandwidth — masked 32-lane reads are strictly cheaper).
// R14: MFMA accumulation split into TWO independent 2-deep chains (kc{0,2},
// kc{1,3}) summed at the end — halves the dependent-MFMA chain latency and
// lets chain 0 start at lgkmcnt(2) instead of lgkmcnt(0).
// ONE barrier per step; ping-pong h buffers; step pair shares float2 x loads.
__launch_bounds__(512, 2)
__global__ void ltc_kernel(const float* __restrict__ x,
                           const float* __restrict__ W_xh,
                           const float* __restrict__ W_hh,
                           const float* __restrict__ b_hh,
                           const float* __restrict__ log_tau,
                           const float* __restrict__ fc_W,
                           const float* __restrict__ fc_b,
                           float* __restrict__ out) {
  __shared__ alignas(16) unsigned short sh_h[2][NROWS][HPAD];  // ping-pong h bf16
  __shared__ alignas(16) float sh_p[NROWS][PPAD];              // final h fp32 for head

  const int tid  = threadIdx.x;
  const int w    = tid >> 6;        // wave 0..7 -> j-tile [w*16, w*16+16)
  const int lane = tid & 63;
  const int quad = lane >> 4;       // 0..3
  const int l16  = lane & 15;       // b-column in B/D fragments
  const int rb0  = blockIdx.x * NROWS;

  // ---- zero both h buffers ----
  {
    uint4* p = (uint4*)&sh_h[0][0][0];
    const int n16 = (2 * NROWS * HPAD) / 8;  // shorts -> uint4 count
    for (int i = tid; i < n16; i += 512) p[i] = make_uint4(0, 0, 0, 0);
  }

  // ---- W_hh A-fragments (PRESCALE*W, RNE bf16), register-resident ----
  // A[m=l16][k = kc*32 + quad*8 + i],  j = w*16 + m
  short8 wa[4];
  {
    const int j = w * 16 + l16;
#pragma unroll
    for (int kc = 0; kc < 4; ++kc) {
      const float* src = W_hh + j * H + kc * 32 + quad * 8;
#pragma unroll
      for (int i = 0; i < 8; ++i)
        wa[kc][i] = (short)f2bf(src[i] * PRESCALE);
    }
  }

  // ---- dense epilogue mapping: lane owns (b = l16&7, j = w*16+quad*4+(l16>>3)*2+{0,1}) ----
  const int brow = l16 & 7;
  const int rbse = (l16 >> 3) * 2;            // 0 for lanes b, 2 for partner lanes b+8
  float ewx[2][3], ebh[2], ecc[2], ea[2], encc2[2];
#pragma unroll
  for (int r = 0; r < 2; ++r) {
    const int j = w * 16 + quad * 4 + rbse + r;
    ewx[r][0] = W_xh[j * 3 + 0] * PRESCALE;
    ewx[r][1] = W_xh[j * 3 + 1] * PRESCALE;
    ewx[r][2] = W_xh[j * 3 + 2] * PRESCALE;
    ebh[r]    = b_hh[j] * PRESCALE;
    float lt  = log_tau[j];
    float tau = logf(1.f + expf(lt)) + 0.001f;   // softplus + eps, exact fp32, once
    float cc  = DT_C / tau;
    ecc[r]    = cc;
    ea[r]     = 1.f - cc;
    encc2[r]  = -2.f * cc;
  }
  const bool lowhalf = (l16 < 8);
  const float* xp = x + (size_t)(rb0 + brow) * (S_LEN * DIN);

  float hreg[2] = {0.f, 0.f};  // fp32 h for (brow, j..j+1), register-resident

  // static LDS offsets (shorts)
  const int rd_off = l16 * HPAD + quad * 8;                     // B-frag read (+ kc*32), l16<8
  const int wr_off = brow * HPAD + w * 16 + quad * 4 + rbse;    // dense 4B h' store
  const unsigned short* __restrict__ buf0 = &sh_h[0][0][0];
  unsigned short* __restrict__ buf1 = &sh_h[1][0][0];

  // persistent B-frag regs: zeroed ONCE; lanes l16>=8 never overwrite them
  short8 bf[4];
#pragma unroll
  for (int kc = 0; kc < 4; ++kc) bf[kc] = short8{0, 0, 0, 0, 0, 0, 0, 0};

  // x prefetch: 6 floats per 2-step pair as 3x float2 (24B step-pair stride)
  float2 pfa = *(const float2*)(xp);
  float2 pfb = *(const float2*)(xp + 2);
  float2 pfc = *(const float2*)(xp + 4);

  __syncthreads();

  auto do_step = [&](const unsigned short* __restrict__ cur,
                     unsigned short* __restrict__ nxt,
                     float xc0, float xc1, float xc2) {
    // B-fragments of h^T (masked; lanes >=8 keep zeros)
    if (l16 < NROWS) {
#pragma unroll
      for (int kc = 0; kc < 4; ++kc)
        bf[kc] = *(const short8*)(cur + rd_off + kc * 32);
    }

    // x-projection terms for this lane's 2 elems (hidden under ds_read latency)
    float t0 = __builtin_fmaf(xc2, ewx[0][2], ebh[0]);
    t0 = __builtin_fmaf(xc1, ewx[0][1], t0);
    t0 = __builtin_fmaf(xc0, ewx[0][0], t0);
    float t1 = __builtin_fmaf(xc2, ewx[1][2], ebh[1]);
    t1 = __builtin_fmaf(xc1, ewx[1][1], t1);
    t1 = __builtin_fmaf(xc0, ewx[1][0], t1);

    // TWO independent 2-deep MFMA chains (halves dependent-chain latency)
    f32x4 a0 = {0.f, 0.f, 0.f, 0.f};
    f32x4 a1 = {0.f, 0.f, 0.f, 0.f};
    a0 = __builtin_amdgcn_mfma_f32_16x16x32_bf16(wa[0], bf[0], a0, 0, 0, 0);
    a1 = __builtin_amdgcn_mfma_f32_16x16x32_bf16(wa[1], bf[1], a1, 0, 0, 0);
    a0 = __builtin_amdgcn_mfma_f32_16x16x32_bf16(wa[2], bf[2], a0, 0, 0, 0);
    a1 = __builtin_amdgcn_mfma_f32_16x16x32_bf16(wa[3], bf[3], a1, 0, 0, 0);
    float s0 = a0[0] + a1[0];
    float s1 = a0[1] + a1[1];
    float s2 = a0[2] + a1[2];
    float s3 = a0[3] + a1[3];

    // DPP pair-exchange: partner lanes (l16>=8) receive r=2,3 from lane l16-8
    float d2 = dpp_xor8(s2);
    float d3 = dpp_xor8(s3);
    float pre0 = lowhalf ? s0 : d2;
    float pre1 = lowhalf ? s1 : d3;

    // dense epilogue: 2 elems/lane, every lane
    {
      float e  = __builtin_amdgcn_exp2f(pre0 + t0);
      float rc = __builtin_amdgcn_rcpf(e + 1.f);
      hreg[0] = __builtin_fmaf(encc2[0], rc, __builtin_fmaf(hreg[0], ea[0], ecc[0]));
    }
    {
      float e  = __builtin_amdgcn_exp2f(pre1 + t1);
      float rc = __builtin_amdgcn_rcpf(e + 1.f);
      hreg[1] = __builtin_fmaf(encc2[1], rc, __builtin_fmaf(hreg[1], ea[1], ecc[1]));
    }

    *(unsigned int*)(nxt + wr_off) = pack2_bf16(hreg[0], hreg[1]);  // dense 4B store
    __syncthreads();
  };

  for (int s = 0; s < S_LEN; s += 2) {
    float2 xa = pfa, xb = pfb, xc = pfc;
    if (s + 2 < S_LEN) {           // uniform branch; prefetch next pair
      xp += 6;
      pfa = *(const float2*)(xp);
      pfb = *(const float2*)(xp + 2);
      pfc = *(const float2*)(xp + 4);
    }
    do_step(buf0, buf1, xa.x, xa.y, xb.x);
    do_step(buf1, (unsigned short*)buf0, xb.y, xc.x, xc.y);
  }

  // ---- final head: params = softplus(h @ fc_W^T + fc_b), [8 x 6] per block ----
  {
    float2 v = make_float2(hreg[0], hreg[1]);
    *(float2*)&sh_p[brow][w * 16 + quad * 4 + rbse] = v;   // 8B-aligned, all lanes distinct
  }
  __syncthreads();

  if (tid < NROWS * DOUT) {
    const int b = tid / DOUT;
    const int o = tid - b * DOUT;
    const float* fw = fc_W + o * H;
    float acc = fc_b[o];
#pragma unroll 4
    for (int k = 0; k < H; ++k) acc += sh_p[b][k] * fw[k];
    float sp = (acc > 15.f) ? acc : logf(1.f + expf(acc));
    out[(rb0 + b) * DOUT + o] = sp;
  }
}

extern "C" void kernel_launch(void* const* d_in, const int* in_sizes, int n_in,
                              void* d_out, int out_size, void* d_ws, size_t ws_size,
                              hipStream_t stream) {
  const float* x       = (const float*)d_in[0];
  const float* W_xh    = (const float*)d_in[1];
  const float* W_hh    = (const float*)d_in[2];
  const float* b_hh    = (const float*)d_in[3];
  const float* log_tau = (const float*)d_in[4];
  const float* fc_W    = (const float*)d_in[5];
  const float* fc_b    = (const float*)d_in[6];
  float* out           = (float*)d_out;

  ltc_kernel<<<dim3(B_TOT / NROWS), dim3(512), 0, stream>>>(
      x, W_xh, W_hh, b_hh, log_tau, fc_W, fc_b, out);
}